// Round 1
// baseline (628.655 us; speedup 1.0000x reference)
//
#include <hip/hip_runtime.h>
#include <math.h>

#define N_NODES 50000
#define N_EDGES 1000000
#define F_IN 128
#define HID 16
#define N_CLS 40
#define HEADS 8
#define ET (N_EDGES + N_NODES)

__device__ __forceinline__ float sel4(float a, float b, float c, float d, int i) {
  float r = a;
  r = (i == 1) ? b : r;
  r = (i == 2) ? c : r;
  r = (i == 3) ? d : r;
  return r;
}

// ---------------- CSR build ----------------

__global__ void k_hist(const int* __restrict__ ei, int* __restrict__ deg) {
  int i = blockIdx.x * blockDim.x + threadIdx.x;
  if (i >= ET) return;
  int d = (i < N_EDGES) ? ei[N_EDGES + i] : (i - N_EDGES);
  atomicAdd(&deg[d], 1);
}

__global__ __launch_bounds__(1024) void k_scan(const int* __restrict__ deg,
                                               int* __restrict__ start) {
  __shared__ int sums[1024];
  const int CH = (N_NODES + 1023) / 1024;
  int t = threadIdx.x;
  int lo = t * CH;
  int hi = lo + CH; if (hi > N_NODES) hi = N_NODES;
  int s = 0;
  for (int i = lo; i < hi; i++) s += deg[i];
  sums[t] = s;
  __syncthreads();
  for (int off = 1; off < 1024; off <<= 1) {
    int v = (t >= off) ? sums[t - off] : 0;
    __syncthreads();
    sums[t] += v;
    __syncthreads();
  }
  int base = (t == 0) ? 0 : sums[t - 1];
  for (int i = lo; i < hi; i++) { start[i] = base; base += deg[i]; }
  if (t == 0) start[N_NODES] = ET;
}

__global__ void k_scatter(const int* __restrict__ ei, const int* __restrict__ start,
                          int* __restrict__ cursor, int* __restrict__ esrc) {
  int i = blockIdx.x * blockDim.x + threadIdx.x;
  if (i >= ET) return;
  int s, d;
  if (i < N_EDGES) { s = ei[i]; d = ei[N_EDGES + i]; }
  else { s = i - N_EDGES; d = s; }
  int pos = atomicAdd(&cursor[d], 1);
  esrc[start[d] + pos] = s;
}

// ---------------- conv1 node transform: h1 = x @ W1, + att dots ----------------

__global__ __launch_bounds__(256) void k_xform1(
    const float* __restrict__ x, const float* __restrict__ W1,
    const float* __restrict__ att_s, const float* __restrict__ att_d,
    float* __restrict__ h1, float* __restrict__ as1, float* __restrict__ ad1) {
  __shared__ float wlds[F_IN * 128];
  __shared__ float xlds[64][F_IN];
  int t = threadIdx.x;
  int base = blockIdx.x * 64;
  for (int i = t; i < F_IN * 128; i += 256) wlds[i] = W1[i];
  for (int i = t; i < 64 * F_IN; i += 256) {
    int n = base + (i >> 7);
    xlds[i >> 7][i & 127] = (n < N_NODES) ? x[(size_t)n * F_IN + (i & 127)] : 0.f;
  }
  __syncthreads();
  int c = t & 127, slot = t >> 7;
  float asv = att_s[c], adv = att_d[c];
  for (int g = 0; g < 64; g += 8) {
    int nb = g + slot * 4;
    float a0 = 0.f, a1 = 0.f, a2 = 0.f, a3 = 0.f;
#pragma unroll 4
    for (int k = 0; k < F_IN; k++) {
      float w = wlds[k * 128 + c];
      a0 += xlds[nb + 0][k] * w;
      a1 += xlds[nb + 1][k] * w;
      a2 += xlds[nb + 2][k] * w;
      a3 += xlds[nb + 3][k] * w;
    }
    float av[4] = {a0, a1, a2, a3};
#pragma unroll
    for (int j = 0; j < 4; j++) {
      int n = base + nb + j;
      if (n < N_NODES) {
        h1[(size_t)n * 128 + c] = av[j];
        float s = av[j] * asv, dd = av[j] * adv;
#pragma unroll
        for (int off = 8; off; off >>= 1) {
          s += __shfl_xor(s, off, 16);
          dd += __shfl_xor(dd, off, 16);
        }
        if ((c & 15) == 0) {
          as1[n * 8 + (c >> 4)] = s;
          ad1[n * 8 + (c >> 4)] = dd;
        }
      }
    }
  }
}

// ---------------- conv1 aggregation (one wave per dst) ----------------

__global__ __launch_bounds__(256) void k_agg1(
    const float* __restrict__ h1, const float* __restrict__ as1,
    const float* __restrict__ ad1, const int* __restrict__ start,
    const int* __restrict__ esrc, const float* __restrict__ b1,
    float* __restrict__ h1out) {
  int wave = threadIdx.x >> 6, lane = threadIdx.x & 63;
  int d = blockIdx.x * 4 + wave;
  if (d >= N_NODES) return;
  int s0 = start[d];
  int deg = start[d + 1] - s0;

  float4 av0 = *(const float4*)(ad1 + d * 8);
  float4 av1 = *(const float4*)(ad1 + d * 8 + 4);
  float ad[8] = {av0.x, av0.y, av0.z, av0.w, av1.x, av1.y, av1.z, av1.w};

  float m[8], den[8];
#pragma unroll
  for (int h = 0; h < 8; h++) { m[h] = -1e30f; den[h] = 0.f; }

  // pass 1: per-head segment max
  for (int i = lane; i < deg; i += 64) {
    int s = esrc[s0 + i];
    float4 p0 = *(const float4*)(as1 + s * 8);
    float4 p1 = *(const float4*)(as1 + s * 8 + 4);
    float e[8] = {p0.x, p0.y, p0.z, p0.w, p1.x, p1.y, p1.z, p1.w};
#pragma unroll
    for (int h = 0; h < 8; h++) {
      float v = e[h] + ad[h];
      v = v > 0.f ? v : 0.2f * v;
      m[h] = fmaxf(m[h], v);
    }
  }
#pragma unroll
  for (int h = 0; h < 8; h++) {
#pragma unroll
    for (int off = 32; off; off >>= 1) m[h] = fmaxf(m[h], __shfl_xor(m[h], off));
  }

  // pass 2: denom
  for (int i = lane; i < deg; i += 64) {
    int s = esrc[s0 + i];
    float4 p0 = *(const float4*)(as1 + s * 8);
    float4 p1 = *(const float4*)(as1 + s * 8 + 4);
    float e[8] = {p0.x, p0.y, p0.z, p0.w, p1.x, p1.y, p1.z, p1.w};
#pragma unroll
    for (int h = 0; h < 8; h++) {
      float v = e[h] + ad[h];
      v = v > 0.f ? v : 0.2f * v;
      den[h] += __expf(v - m[h]);
    }
  }
#pragma unroll
  for (int h = 0; h < 8; h++) {
#pragma unroll
    for (int off = 32; off; off >>= 1) den[h] += __shfl_xor(den[h], off);
  }
  float inv[8];
#pragma unroll
  for (int h = 0; h < 8; h++) inv[h] = 1.f / (den[h] + 1e-16f);

  // pass 3: channel-parallel message accumulation (serial over edges)
  int h0 = lane >> 4;  // heads: acc0 -> h0, acc1 -> h0+4
  float mA = sel4(m[0], m[1], m[2], m[3], h0);
  float mB = sel4(m[4], m[5], m[6], m[7], h0);
  float iA = sel4(inv[0], inv[1], inv[2], inv[3], h0);
  float iB = sel4(inv[4], inv[5], inv[6], inv[7], h0);
  float dA = sel4(ad[0], ad[1], ad[2], ad[3], h0);
  float dB = sel4(ad[4], ad[5], ad[6], ad[7], h0);

  float acc0 = 0.f, acc1 = 0.f;
  for (int i = 0; i < deg; i++) {
    int s = esrc[s0 + i];
    float eA = as1[s * 8 + h0] + dA;     eA = eA > 0.f ? eA : 0.2f * eA;
    float eB = as1[s * 8 + 4 + h0] + dB; eB = eB > 0.f ? eB : 0.2f * eB;
    float aA = __expf(eA - mA) * iA;
    float aB = __expf(eB - mB) * iB;
    acc0 += h1[(size_t)s * 128 + lane] * aA;
    acc1 += h1[(size_t)s * 128 + 64 + lane] * aB;
  }

  // mean over 8 heads + bias + ELU
  float v = acc0 + acc1;
  v += __shfl_xor(v, 16);
  v += __shfl_xor(v, 32);
  if (lane < 16) {
    float r = v * 0.125f + b1[lane];
    r = r > 0.f ? r : __expf(r) - 1.f;
    h1out[d * 16 + lane] = r;
  }
}

// ---------------- conv2 node transform ----------------

__global__ __launch_bounds__(256) void k_xform2(
    const float* __restrict__ h1out, const float* __restrict__ W2,
    const float* __restrict__ att_s2, const float* __restrict__ att_d2,
    float* __restrict__ h2, float* __restrict__ as2, float* __restrict__ ad2) {
  int wave = threadIdx.x >> 6, lane = threadIdx.x & 63;
  int n = blockIdx.x * 4 + wave;
  if (n >= N_NODES) return;
  float acc = 0.f;
  if (lane < N_CLS) {
#pragma unroll
    for (int k = 0; k < HID; k++) acc += h1out[n * HID + k] * W2[k * N_CLS + lane];
    h2[n * N_CLS + lane] = acc;
  }
  float sv = (lane < N_CLS) ? acc * att_s2[lane] : 0.f;
  float dv = (lane < N_CLS) ? acc * att_d2[lane] : 0.f;
#pragma unroll
  for (int off = 32; off; off >>= 1) {
    sv += __shfl_xor(sv, off);
    dv += __shfl_xor(dv, off);
  }
  if (lane == 0) { as2[n] = sv; ad2[n] = dv; }
}

// ---------------- conv2 aggregation + bias + log_softmax ----------------

__global__ __launch_bounds__(256) void k_agg2(
    const float* __restrict__ h2, const float* __restrict__ as2,
    const float* __restrict__ ad2, const int* __restrict__ start,
    const int* __restrict__ esrc, const float* __restrict__ b2,
    float* __restrict__ out) {
  int wave = threadIdx.x >> 6, lane = threadIdx.x & 63;
  int d = blockIdx.x * 4 + wave;
  if (d >= N_NODES) return;
  int s0 = start[d];
  int deg = start[d + 1] - s0;
  float adv = ad2[d];

  float m = -1e30f;
  for (int i = lane; i < deg; i += 64) {
    float e = as2[esrc[s0 + i]] + adv;
    e = e > 0.f ? e : 0.2f * e;
    m = fmaxf(m, e);
  }
#pragma unroll
  for (int off = 32; off; off >>= 1) m = fmaxf(m, __shfl_xor(m, off));

  float den = 0.f;
  for (int i = lane; i < deg; i += 64) {
    float e = as2[esrc[s0 + i]] + adv;
    e = e > 0.f ? e : 0.2f * e;
    den += __expf(e - m);
  }
#pragma unroll
  for (int off = 32; off; off >>= 1) den += __shfl_xor(den, off);
  float iv = 1.f / (den + 1e-16f);

  float acc = 0.f;
  for (int i = 0; i < deg; i++) {
    int s = esrc[s0 + i];
    float e = as2[s] + adv;
    e = e > 0.f ? e : 0.2f * e;
    float alpha = __expf(e - m) * iv;
    if (lane < N_CLS) acc += h2[s * N_CLS + lane] * alpha;
  }

  float v = (lane < N_CLS) ? acc + b2[lane] : -1e30f;
  float mx = v;
#pragma unroll
  for (int off = 32; off; off >>= 1) mx = fmaxf(mx, __shfl_xor(mx, off));
  float ex = (lane < N_CLS) ? __expf(v - mx) : 0.f;
  float sm = ex;
#pragma unroll
  for (int off = 32; off; off >>= 1) sm += __shfl_xor(sm, off);
  float lse = logf(sm);
  if (lane < N_CLS) out[d * N_CLS + lane] = (v - mx) - lse;
}

// ---------------- host launcher ----------------

extern "C" void kernel_launch(void* const* d_in, const int* in_sizes, int n_in,
                              void* d_out, int out_size, void* d_ws, size_t ws_size,
                              hipStream_t stream) {
  const float* x    = (const float*)d_in[0];
  const int*   ei   = (const int*)d_in[1];
  const float* W1   = (const float*)d_in[2];
  const float* as1w = (const float*)d_in[3];
  const float* ad1w = (const float*)d_in[4];
  const float* b1   = (const float*)d_in[5];
  const float* W2   = (const float*)d_in[6];
  const float* as2w = (const float*)d_in[7];
  const float* ad2w = (const float*)d_in[8];
  const float* b2   = (const float*)d_in[9];
  float* out = (float*)d_out;

  char* ws = (char*)d_ws;
  size_t off = 0;
  auto alloc = [&](size_t bytes) -> void* {
    void* p = ws + off;
    off += (bytes + 255) & ~(size_t)255;
    return p;
  };
  float* h1    = (float*)alloc((size_t)N_NODES * 128 * 4);
  float* as1   = (float*)alloc((size_t)N_NODES * 8 * 4);
  float* ad1   = (float*)alloc((size_t)N_NODES * 8 * 4);
  float* h1out = (float*)alloc((size_t)N_NODES * 16 * 4);
  float* h2    = (float*)alloc((size_t)N_NODES * 40 * 4);
  float* as2   = (float*)alloc((size_t)N_NODES * 4);
  float* ad2   = (float*)alloc((size_t)N_NODES * 4);
  int* deg     = (int*)alloc((size_t)N_NODES * 4);
  int* start   = (int*)alloc((size_t)(N_NODES + 1) * 4);
  int* cursor  = (int*)alloc((size_t)N_NODES * 4);
  int* esrc    = (int*)alloc((size_t)ET * 4);

  hipMemsetAsync(deg, 0, (size_t)N_NODES * 4, stream);
  hipMemsetAsync(cursor, 0, (size_t)N_NODES * 4, stream);

  int eb = (ET + 255) / 256;
  k_hist<<<eb, 256, 0, stream>>>(ei, deg);
  k_scan<<<1, 1024, 0, stream>>>(deg, start);
  k_scatter<<<eb, 256, 0, stream>>>(ei, start, cursor, esrc);

  k_xform1<<<(N_NODES + 63) / 64, 256, 0, stream>>>(x, W1, as1w, ad1w, h1, as1, ad1);
  k_agg1<<<(N_NODES + 3) / 4, 256, 0, stream>>>(h1, as1, ad1, start, esrc, b1, h1out);
  k_xform2<<<(N_NODES + 3) / 4, 256, 0, stream>>>(h1out, W2, as2w, ad2w, h2, as2, ad2);
  k_agg2<<<(N_NODES + 3) / 4, 256, 0, stream>>>(h2, as2, ad2, start, esrc, b2, out);
}

// Round 4
// 505.506 us; speedup vs baseline: 1.2436x; 1.2436x over previous
//
#include <hip/hip_runtime.h>
#include <math.h>

#define N_NODES 50000
#define N_EDGES 1000000
#define F_IN 128
#define HID 16
#define N_CLS 40
#define HEADS 8
#define ET (N_EDGES + N_NODES)

__device__ __forceinline__ void fma4(float4& acc, float s, const float4& v) {
  acc.x += s * v.x;
  acc.y += s * v.y;
  acc.z += s * v.z;
  acc.w += s * v.w;
}

__device__ __forceinline__ float dot4(float4 a, float4 b) {
  return a.x * b.x + a.y * b.y + a.z * b.z + a.w * b.w;
}

// ---------------- CSR build ----------------

__global__ void k_hist(const int* __restrict__ ei, int* __restrict__ deg) {
  int i = blockIdx.x * blockDim.x + threadIdx.x;
  if (i >= ET) return;
  int d = (i < N_EDGES) ? ei[N_EDGES + i] : (i - N_EDGES);
  atomicAdd(&deg[d], 1);
}

__global__ __launch_bounds__(1024) void k_scan(const int* __restrict__ deg,
                                               int* __restrict__ start) {
  __shared__ int sums[1024];
  const int CH = (N_NODES + 1023) / 1024;
  int t = threadIdx.x;
  int lo = t * CH;
  int hi = lo + CH; if (hi > N_NODES) hi = N_NODES;
  int s = 0;
  for (int i = lo; i < hi; i++) s += deg[i];
  sums[t] = s;
  __syncthreads();
  for (int off = 1; off < 1024; off <<= 1) {
    int v = (t >= off) ? sums[t - off] : 0;
    __syncthreads();
    sums[t] += v;
    __syncthreads();
  }
  int base = (t == 0) ? 0 : sums[t - 1];
  for (int i = lo; i < hi; i++) { start[i] = base; base += deg[i]; }
  if (t == 0) start[N_NODES] = ET;
}

__global__ void k_scatter(const int* __restrict__ ei, const int* __restrict__ start,
                          int* __restrict__ cursor, int* __restrict__ esrc) {
  int i = blockIdx.x * blockDim.x + threadIdx.x;
  if (i >= ET) return;
  int s, d;
  if (i < N_EDGES) { s = ei[i]; d = ei[N_EDGES + i]; }
  else { s = i - N_EDGES; d = s; }
  int pos = atomicAdd(&cursor[d], 1);
  esrc[start[d] + pos] = s;
}

// ---------------- conv1 node transform: h1 = x @ W1, fused att dots ----------------
// block: 64 nodes x 128 channels, 256 threads, thread = 4 nodes x 8 channels.
// LDS: x tile 32KB + W half-tile 32KB = 64KB -> 2 blocks/CU.

__global__ __launch_bounds__(256) void k_xform1(
    const float* __restrict__ x, const float* __restrict__ W1,
    const float* __restrict__ att_s, const float* __restrict__ att_d,
    float* __restrict__ h1, float* __restrict__ as1, float* __restrict__ ad1) {
  __shared__ float4 xlds[64 * 32];  // [node][k/4]
  __shared__ float4 wlds[64 * 32];  // [k_local][c/4]
  int t = threadIdx.x;
  int tx = t & 15, ty = t >> 4;
  int base = blockIdx.x * 64;
  const float4* x4 = (const float4*)x;
  const float4* W4 = (const float4*)W1;

  // stage x tile (coalesced)
  for (int i = t; i < 64 * 32; i += 256) {
    int n = i >> 5;
    int gn = base + n;
    float4 v = {0.f, 0.f, 0.f, 0.f};
    if (gn < N_NODES) v = x4[(size_t)gn * 32 + (i & 31)];
    xlds[i] = v;
  }

  float4 accA[4], accB[4];
#pragma unroll
  for (int n = 0; n < 4; n++) {
    accA[n] = {0.f, 0.f, 0.f, 0.f};
    accB[n] = {0.f, 0.f, 0.f, 0.f};
  }
  int n0 = ty * 4;

  for (int half = 0; half < 2; half++) {
    __syncthreads();  // xlds ready (half 0) / previous compute done (half 1)
    for (int i = t; i < 64 * 32; i += 256)
      wlds[i] = W4[(size_t)(half * 64 + (i >> 5)) * 32 + (i & 31)];
    __syncthreads();
#pragma unroll
    for (int kk = 0; kk < 64; kk += 4) {
      int kq = half * 16 + (kk >> 2);
      float4 xv0 = xlds[(n0 + 0) * 32 + kq];
      float4 xv1 = xlds[(n0 + 1) * 32 + kq];
      float4 xv2 = xlds[(n0 + 2) * 32 + kq];
      float4 xv3 = xlds[(n0 + 3) * 32 + kq];
#pragma unroll
      for (int j = 0; j < 4; j++) {
        float4 wA = wlds[(kk + j) * 32 + tx * 2];
        float4 wB = wlds[(kk + j) * 32 + tx * 2 + 1];
        float s0 = (j == 0) ? xv0.x : (j == 1) ? xv0.y : (j == 2) ? xv0.z : xv0.w;
        float s1 = (j == 0) ? xv1.x : (j == 1) ? xv1.y : (j == 2) ? xv1.z : xv1.w;
        float s2 = (j == 0) ? xv2.x : (j == 1) ? xv2.y : (j == 2) ? xv2.z : xv2.w;
        float s3 = (j == 0) ? xv3.x : (j == 1) ? xv3.y : (j == 2) ? xv3.z : xv3.w;
        fma4(accA[0], s0, wA); fma4(accB[0], s0, wB);
        fma4(accA[1], s1, wA); fma4(accB[1], s1, wB);
        fma4(accA[2], s2, wA); fma4(accB[2], s2, wB);
        fma4(accA[3], s3, wA); fma4(accB[3], s3, wB);
      }
    }
  }

  // epilogue: store h1, fused att_src/att_dst dots
  int c0 = tx * 8;
  float4 asA = *(const float4*)(att_s + c0);
  float4 asB = *(const float4*)(att_s + c0 + 4);
  float4 adA = *(const float4*)(att_d + c0);
  float4 adB = *(const float4*)(att_d + c0 + 4);
  float4* h1_4 = (float4*)h1;
#pragma unroll
  for (int n = 0; n < 4; n++) {
    int gn = base + n0 + n;
    float ps = dot4(accA[n], asA) + dot4(accB[n], asB);
    float pd = dot4(accA[n], adA) + dot4(accB[n], adB);
    ps += __shfl_xor(ps, 1);
    pd += __shfl_xor(pd, 1);
    if (gn < N_NODES) {
      h1_4[(size_t)gn * 32 + tx * 2] = accA[n];
      h1_4[(size_t)gn * 32 + tx * 2 + 1] = accB[n];
      if ((tx & 1) == 0) {
        as1[gn * 8 + (tx >> 1)] = ps;
        ad1[gn * 8 + (tx >> 1)] = pd;
      }
    }
  }
}

// ---------------- conv1 aggregation (one wave per dst) + fused conv2 transform ----------------

__global__ __launch_bounds__(256) void k_agg1(
    const float* __restrict__ h1, const float* __restrict__ as1,
    const float* __restrict__ ad1, const int* __restrict__ start,
    const int* __restrict__ esrc, const float* __restrict__ b1,
    const float* __restrict__ W2, const float* __restrict__ att_s2,
    const float* __restrict__ att_d2,
    float* __restrict__ h2, float* __restrict__ as2, float* __restrict__ ad2) {
  int wave = threadIdx.x >> 6, lane = threadIdx.x & 63;
  int d = blockIdx.x * 4 + wave;
  if (d >= N_NODES) return;
  int s0 = start[d];
  int deg = start[d + 1] - s0;

  float4 av0 = *(const float4*)(ad1 + d * 8);
  float4 av1 = *(const float4*)(ad1 + d * 8 + 4);
  float ad[8] = {av0.x, av0.y, av0.z, av0.w, av1.x, av1.y, av1.z, av1.w};

  // single online pass: per-head running max + denom per lane
  float m[8], den[8];
#pragma unroll
  for (int h = 0; h < 8; h++) { m[h] = -1e30f; den[h] = 0.f; }
  for (int i = lane; i < deg; i += 64) {
    int s = esrc[s0 + i];
    float4 p0 = *(const float4*)(as1 + s * 8);
    float4 p1 = *(const float4*)(as1 + s * 8 + 4);
    float e[8] = {p0.x, p0.y, p0.z, p0.w, p1.x, p1.y, p1.z, p1.w};
#pragma unroll
    for (int h = 0; h < 8; h++) {
      float v = e[h] + ad[h];
      v = v > 0.f ? v : 0.2f * v;
      float nm = fmaxf(m[h], v);
      den[h] = den[h] * __expf(m[h] - nm) + __expf(v - nm);
      m[h] = nm;
    }
  }
  // cross-lane combine
#pragma unroll
  for (int h = 0; h < 8; h++) {
#pragma unroll
    for (int off = 32; off; off >>= 1) {
      float om = __shfl_xor(m[h], off);
      float od = __shfl_xor(den[h], off);
      float nm = fmaxf(m[h], om);
      den[h] = den[h] * __expf(m[h] - nm) + od * __expf(om - nm);
      m[h] = nm;
    }
  }
  float inv[8];
#pragma unroll
  for (int h = 0; h < 8; h++) inv[h] = 1.f / (den[h] + 1e-16f);

  // pass 2: channel-parallel message accumulation (serial over edges)
  int h0 = lane >> 4;
  float mA = (h0 == 0) ? m[0] : (h0 == 1) ? m[1] : (h0 == 2) ? m[2] : m[3];
  float mB = (h0 == 0) ? m[4] : (h0 == 1) ? m[5] : (h0 == 2) ? m[6] : m[7];
  float iA = (h0 == 0) ? inv[0] : (h0 == 1) ? inv[1] : (h0 == 2) ? inv[2] : inv[3];
  float iB = (h0 == 0) ? inv[4] : (h0 == 1) ? inv[5] : (h0 == 2) ? inv[6] : inv[7];
  float dA = (h0 == 0) ? ad[0] : (h0 == 1) ? ad[1] : (h0 == 2) ? ad[2] : ad[3];
  float dB = (h0 == 0) ? ad[4] : (h0 == 1) ? ad[5] : (h0 == 2) ? ad[6] : ad[7];

  float acc0 = 0.f, acc1 = 0.f;
  for (int i = 0; i < deg; i++) {
    int s = esrc[s0 + i];
    float eA = as1[s * 8 + h0] + dA;     eA = eA > 0.f ? eA : 0.2f * eA;
    float eB = as1[s * 8 + 4 + h0] + dB; eB = eB > 0.f ? eB : 0.2f * eB;
    float aA = __expf(eA - mA) * iA;
    float aB = __expf(eB - mB) * iB;
    acc0 += h1[(size_t)s * 128 + lane] * aA;
    acc1 += h1[(size_t)s * 128 + 64 + lane] * aB;
  }

  // mean over 8 heads + bias + ELU -> every lane holds channel (lane&15)
  float v = acc0 + acc1;
  v += __shfl_xor(v, 16);
  v += __shfl_xor(v, 32);
  float r = v * 0.125f + b1[lane & 15];
  r = r > 0.f ? r : __expf(r) - 1.f;

  // fused conv2 node transform: h2[d][j] = sum_k r_k W2[k][j], j = lane < 40
  float acc2 = 0.f;
#pragma unroll
  for (int k = 0; k < 16; k++) {
    float rk = __shfl(r, k);
    if (lane < N_CLS) acc2 += rk * W2[k * N_CLS + lane];
  }
  float sv = 0.f, dv = 0.f;
  if (lane < N_CLS) {
    h2[d * N_CLS + lane] = acc2;
    sv = acc2 * att_s2[lane];
    dv = acc2 * att_d2[lane];
  }
#pragma unroll
  for (int off = 32; off; off >>= 1) {
    sv += __shfl_xor(sv, off);
    dv += __shfl_xor(dv, off);
  }
  if (lane == 0) { as2[d] = sv; ad2[d] = dv; }
}

// ---------------- conv2 aggregation + bias + log_softmax ----------------

__global__ __launch_bounds__(256) void k_agg2(
    const float* __restrict__ h2, const float* __restrict__ as2,
    const float* __restrict__ ad2, const int* __restrict__ start,
    const int* __restrict__ esrc, const float* __restrict__ b2,
    float* __restrict__ out) {
  int wave = threadIdx.x >> 6, lane = threadIdx.x & 63;
  int d = blockIdx.x * 4 + wave;
  if (d >= N_NODES) return;
  int s0 = start[d];
  int deg = start[d + 1] - s0;
  float adv = ad2[d];

  // online max+denom in one pass
  float m = -1e30f, den = 0.f;
  for (int i = lane; i < deg; i += 64) {
    float e = as2[esrc[s0 + i]] + adv;
    e = e > 0.f ? e : 0.2f * e;
    float nm = fmaxf(m, e);
    den = den * __expf(m - nm) + __expf(e - nm);
    m = nm;
  }
#pragma unroll
  for (int off = 32; off; off >>= 1) {
    float om = __shfl_xor(m, off);
    float od = __shfl_xor(den, off);
    float nm = fmaxf(m, om);
    den = den * __expf(m - nm) + od * __expf(om - nm);
    m = nm;
  }
  float iv = 1.f / (den + 1e-16f);

  float acc = 0.f;
  for (int i = 0; i < deg; i++) {
    int s = esrc[s0 + i];
    float e = as2[s] + adv;
    e = e > 0.f ? e : 0.2f * e;
    float alpha = __expf(e - m) * iv;
    if (lane < N_CLS) acc += h2[s * N_CLS + lane] * alpha;
  }

  float v = (lane < N_CLS) ? acc + b2[lane] : -1e30f;
  float mx = v;
#pragma unroll
  for (int off = 32; off; off >>= 1) mx = fmaxf(mx, __shfl_xor(mx, off));
  float ex = (lane < N_CLS) ? __expf(v - mx) : 0.f;
  float sm = ex;
#pragma unroll
  for (int off = 32; off; off >>= 1) sm += __shfl_xor(sm, off);
  float lse = logf(sm);
  if (lane < N_CLS) out[d * N_CLS + lane] = (v - mx) - lse;
}

// ---------------- host launcher ----------------

extern "C" void kernel_launch(void* const* d_in, const int* in_sizes, int n_in,
                              void* d_out, int out_size, void* d_ws, size_t ws_size,
                              hipStream_t stream) {
  const float* x    = (const float*)d_in[0];
  const int*   ei   = (const int*)d_in[1];
  const float* W1   = (const float*)d_in[2];
  const float* as1w = (const float*)d_in[3];
  const float* ad1w = (const float*)d_in[4];
  const float* b1   = (const float*)d_in[5];
  const float* W2   = (const float*)d_in[6];
  const float* as2w = (const float*)d_in[7];
  const float* ad2w = (const float*)d_in[8];
  const float* b2   = (const float*)d_in[9];
  float* out = (float*)d_out;

  char* ws = (char*)d_ws;
  size_t off = 0;
  auto alloc = [&](size_t bytes) -> void* {
    void* p = ws + off;
    off += (bytes + 255) & ~(size_t)255;
    return p;
  };
  float* h1    = (float*)alloc((size_t)N_NODES * 128 * 4);
  float* as1   = (float*)alloc((size_t)N_NODES * 8 * 4);
  float* ad1   = (float*)alloc((size_t)N_NODES * 8 * 4);
  float* h2    = (float*)alloc((size_t)N_NODES * 40 * 4);
  float* as2   = (float*)alloc((size_t)N_NODES * 4);
  float* ad2   = (float*)alloc((size_t)N_NODES * 4);
  int* deg     = (int*)alloc((size_t)N_NODES * 4);
  int* start   = (int*)alloc((size_t)(N_NODES + 1) * 4);
  int* cursor  = (int*)alloc((size_t)N_NODES * 4);
  int* esrc    = (int*)alloc((size_t)ET * 4);

  (void)hipMemsetAsync(deg, 0, (size_t)N_NODES * 4, stream);
  (void)hipMemsetAsync(cursor, 0, (size_t)N_NODES * 4, stream);

  int eb = (ET + 255) / 256;
  k_hist<<<eb, 256, 0, stream>>>(ei, deg);
  k_scan<<<1, 1024, 0, stream>>>(deg, start);
  k_scatter<<<eb, 256, 0, stream>>>(ei, start, cursor, esrc);

  k_xform1<<<(N_NODES + 63) / 64, 256, 0, stream>>>(x, W1, as1w, ad1w, h1, as1, ad1);
  k_agg1<<<(N_NODES + 3) / 4, 256, 0, stream>>>(h1, as1, ad1, start, esrc, b1,
                                                W2, as2w, ad2w, h2, as2, ad2);
  k_agg2<<<(N_NODES + 3) / 4, 256, 0, stream>>>(h2, as2, ad2, start, esrc, b2, out);
}

// Round 5
// 359.170 us; speedup vs baseline: 1.7503x; 1.4074x over previous
//
#include <hip/hip_runtime.h>
#include <hip/hip_fp16.h>
#include <math.h>

#define N_NODES 50000
#define N_EDGES 1000000
#define F_IN 128
#define HID 16
#define N_CLS 40
#define HEADS 8
#define ET (N_EDGES + N_NODES)

__device__ __forceinline__ void fma4(float4& acc, float s, const float4& v) {
  acc.x += s * v.x;
  acc.y += s * v.y;
  acc.z += s * v.z;
  acc.w += s * v.w;
}

__device__ __forceinline__ float dot4(float4 a, float4 b) {
  return a.x * b.x + a.y * b.y + a.z * b.z + a.w * b.w;
}

// monotone float<->uint encoding for atomicMax on floats
__device__ __forceinline__ unsigned encf(float f) {
  unsigned b = __float_as_uint(f);
  return (b & 0x80000000u) ? ~b : (b | 0x80000000u);
}
__device__ __forceinline__ float decf(unsigned k) {
  unsigned b = (k & 0x80000000u) ? (k ^ 0x80000000u) : ~k;
  return __uint_as_float(b);
}

// ---------------- CSR build ----------------

__global__ void k_hist(const int* __restrict__ ei, int* __restrict__ deg) {
  int i = blockIdx.x * blockDim.x + threadIdx.x;
  if (i >= ET) return;
  int d = (i < N_EDGES) ? ei[N_EDGES + i] : (i - N_EDGES);
  atomicAdd(&deg[d], 1);
}

__global__ __launch_bounds__(1024) void k_scan(const int* __restrict__ deg,
                                               int* __restrict__ start) {
  __shared__ int sums[1024];
  const int CH = (N_NODES + 1023) / 1024;
  int t = threadIdx.x;
  int lo = t * CH;
  int hi = lo + CH; if (hi > N_NODES) hi = N_NODES;
  int s = 0;
  for (int i = lo; i < hi; i++) s += deg[i];
  sums[t] = s;
  __syncthreads();
  for (int off = 1; off < 1024; off <<= 1) {
    int v = (t >= off) ? sums[t - off] : 0;
    __syncthreads();
    sums[t] += v;
    __syncthreads();
  }
  int base = (t == 0) ? 0 : sums[t - 1];
  for (int i = lo; i < hi; i++) { start[i] = base; base += deg[i]; }
  if (t == 0) start[N_NODES] = ET;
}

__global__ void k_scatter(const int* __restrict__ ei, const int* __restrict__ start,
                          int* __restrict__ cursor, int* __restrict__ esrc) {
  int i = blockIdx.x * blockDim.x + threadIdx.x;
  if (i >= ET) return;
  int s, d;
  if (i < N_EDGES) { s = ei[i]; d = ei[N_EDGES + i]; }
  else { s = i - N_EDGES; d = s; }
  int pos = atomicAdd(&cursor[d], 1);
  esrc[start[d] + pos] = s;
}

// ---------------- conv1 node transform: h1 = x @ W1 (fp16 out), fused att dots ----

__global__ __launch_bounds__(256) void k_xform1(
    const float* __restrict__ x, const float* __restrict__ W1,
    const float* __restrict__ att_s, const float* __restrict__ att_d,
    __half* __restrict__ h1, float* __restrict__ as1, float* __restrict__ ad1) {
  __shared__ float4 xlds[64 * 32];  // [node][k/4]
  __shared__ float4 wlds[64 * 32];  // [k_local][c/4]
  int t = threadIdx.x;
  int tx = t & 15, ty = t >> 4;
  int base = blockIdx.x * 64;
  const float4* x4 = (const float4*)x;
  const float4* W4 = (const float4*)W1;

  for (int i = t; i < 64 * 32; i += 256) {
    int n = i >> 5;
    int gn = base + n;
    float4 v = {0.f, 0.f, 0.f, 0.f};
    if (gn < N_NODES) v = x4[(size_t)gn * 32 + (i & 31)];
    xlds[i] = v;
  }

  float4 accA[4], accB[4];
#pragma unroll
  for (int n = 0; n < 4; n++) {
    accA[n] = {0.f, 0.f, 0.f, 0.f};
    accB[n] = {0.f, 0.f, 0.f, 0.f};
  }
  int n0 = ty * 4;

  for (int half = 0; half < 2; half++) {
    __syncthreads();
    for (int i = t; i < 64 * 32; i += 256)
      wlds[i] = W4[(size_t)(half * 64 + (i >> 5)) * 32 + (i & 31)];
    __syncthreads();
#pragma unroll
    for (int kk = 0; kk < 64; kk += 4) {
      int kq = half * 16 + (kk >> 2);
      float4 xv0 = xlds[(n0 + 0) * 32 + kq];
      float4 xv1 = xlds[(n0 + 1) * 32 + kq];
      float4 xv2 = xlds[(n0 + 2) * 32 + kq];
      float4 xv3 = xlds[(n0 + 3) * 32 + kq];
#pragma unroll
      for (int j = 0; j < 4; j++) {
        float4 wA = wlds[(kk + j) * 32 + tx * 2];
        float4 wB = wlds[(kk + j) * 32 + tx * 2 + 1];
        float s0 = (j == 0) ? xv0.x : (j == 1) ? xv0.y : (j == 2) ? xv0.z : xv0.w;
        float s1 = (j == 0) ? xv1.x : (j == 1) ? xv1.y : (j == 2) ? xv1.z : xv1.w;
        float s2 = (j == 0) ? xv2.x : (j == 1) ? xv2.y : (j == 2) ? xv2.z : xv2.w;
        float s3 = (j == 0) ? xv3.x : (j == 1) ? xv3.y : (j == 2) ? xv3.z : xv3.w;
        fma4(accA[0], s0, wA); fma4(accB[0], s0, wB);
        fma4(accA[1], s1, wA); fma4(accB[1], s1, wB);
        fma4(accA[2], s2, wA); fma4(accB[2], s2, wB);
        fma4(accA[3], s3, wA); fma4(accB[3], s3, wB);
      }
    }
  }

  int c0 = tx * 8;
  float4 asA = *(const float4*)(att_s + c0);
  float4 asB = *(const float4*)(att_s + c0 + 4);
  float4 adA = *(const float4*)(att_d + c0);
  float4 adB = *(const float4*)(att_d + c0 + 4);
#pragma unroll
  for (int n = 0; n < 4; n++) {
    int gn = base + n0 + n;
    float ps = dot4(accA[n], asA) + dot4(accB[n], asB);
    float pd = dot4(accA[n], adA) + dot4(accB[n], adB);
    ps += __shfl_xor(ps, 1);
    pd += __shfl_xor(pd, 1);
    if (gn < N_NODES) {
      uint4 pk;
      __half2* ph = (__half2*)&pk;
      ph[0] = __floats2half2_rn(accA[n].x, accA[n].y);
      ph[1] = __floats2half2_rn(accA[n].z, accA[n].w);
      ph[2] = __floats2half2_rn(accB[n].x, accB[n].y);
      ph[3] = __floats2half2_rn(accB[n].z, accB[n].w);
      *(uint4*)(h1 + (size_t)gn * 128 + tx * 8) = pk;
      if ((tx & 1) == 0) {
        as1[gn * 8 + (tx >> 1)] = ps;
        ad1[gn * 8 + (tx >> 1)] = pd;
      }
    }
  }
}

// ---------------- global per-head max of as1 ----------------

__global__ __launch_bounds__(256) void k_maxas1(const float* __restrict__ as1,
                                                unsigned* __restrict__ enc) {
  int t = blockIdx.x * 256 + threadIdx.x;  // 128 blocks -> 32768 threads
  int h = t & 7;
  float mx = -1e30f;
  for (int r = t >> 3; r < N_NODES; r += 4096) mx = fmaxf(mx, as1[r * 8 + h]);
#pragma unroll
  for (int off = 8; off < 64; off <<= 1) mx = fmaxf(mx, __shfl_xor(mx, off));
  if ((threadIdx.x & 63) < 8) atomicMax(&enc[h], encf(mx));
}

__global__ __launch_bounds__(256) void k_maxas2(const float* __restrict__ as2,
                                                unsigned* __restrict__ enc) {
  int t = blockIdx.x * 256 + threadIdx.x;  // 64 blocks -> 16384 threads
  float mx = -1e30f;
  for (int r = t; r < N_NODES; r += 16384) mx = fmaxf(mx, as2[r]);
#pragma unroll
  for (int off = 32; off; off >>= 1) mx = fmaxf(mx, __shfl_xor(mx, off));
  if ((threadIdx.x & 63) == 0) atomicMax(enc, encf(mx));
}

// ---------------- conv1 aggregation + fused conv2 transform ----------------
// One wave per dst. Chunked: lane-parallel exp phase -> LDS -> serial gather.
// Unnormalized accumulation, single divide at end. Per-dst upper-bound shift c_h.

__global__ __launch_bounds__(256) void k_agg1(
    const __half* __restrict__ h1, const float* __restrict__ as1,
    const float* __restrict__ ad1, const int* __restrict__ start,
    const int* __restrict__ esrc, const float* __restrict__ b1,
    const float* __restrict__ W2, const float* __restrict__ att_s2,
    const float* __restrict__ att_d2, const unsigned* __restrict__ as1maxEnc,
    __half* __restrict__ h2, float* __restrict__ as2, float* __restrict__ ad2) {
  __shared__ float p_lds[4][64][8];
  __shared__ int s_lds[4][64];
  int wave = threadIdx.x >> 6, lane = threadIdx.x & 63;
  int d = blockIdx.x * 4 + wave;
  if (d >= N_NODES) return;
  int s0 = start[d];
  int deg = start[d + 1] - s0;

  float4 av0 = *(const float4*)(ad1 + d * 8);
  float4 av1 = *(const float4*)(ad1 + d * 8 + 4);
  float ad[8] = {av0.x, av0.y, av0.z, av0.w, av1.x, av1.y, av1.z, av1.w};
  float c[8], den[8];
#pragma unroll
  for (int h = 0; h < 8; h++) {
    float e = decf(as1maxEnc[h]) + ad[h];
    c[h] = e > 0.f ? e : 0.2f * e;   // upper bound on leaky(as+ad) over segment
    den[h] = 0.f;
  }

  int hsel = lane >> 3;  // head for this lane's channel pair (2*lane, 2*lane+1)
  float accx = 0.f, accy = 0.f;
  const __half* h1l = h1 + lane * 2;

  for (int be = 0; be < deg; be += 64) {
    int cnt = min(64, deg - be);
    if (lane < cnt) {
      int s = esrc[s0 + be + lane];
      s_lds[wave][lane] = s;
      float4 p0 = *(const float4*)(as1 + s * 8);
      float4 p1 = *(const float4*)(as1 + s * 8 + 4);
      float e[8] = {p0.x, p0.y, p0.z, p0.w, p1.x, p1.y, p1.z, p1.w};
      float pv[8];
#pragma unroll
      for (int h = 0; h < 8; h++) {
        float v = e[h] + ad[h];
        v = v > 0.f ? v : 0.2f * v;
        pv[h] = __expf(v - c[h]);
        den[h] += pv[h];
      }
      *(float4*)&p_lds[wave][lane][0] = make_float4(pv[0], pv[1], pv[2], pv[3]);
      *(float4*)&p_lds[wave][lane][4] = make_float4(pv[4], pv[5], pv[6], pv[7]);
    }
    asm volatile("s_waitcnt lgkmcnt(0)" ::: "memory");
    int i = 0;
    for (; i + 3 < cnt; i += 4) {
      int sA = s_lds[wave][i + 0], sB = s_lds[wave][i + 1];
      int sC = s_lds[wave][i + 2], sD = s_lds[wave][i + 3];
      float pA = p_lds[wave][i + 0][hsel], pB = p_lds[wave][i + 1][hsel];
      float pC = p_lds[wave][i + 2][hsel], pD = p_lds[wave][i + 3][hsel];
      float2 fA = __half22float2(*(const __half2*)(h1l + (size_t)sA * 128));
      float2 fB = __half22float2(*(const __half2*)(h1l + (size_t)sB * 128));
      float2 fC = __half22float2(*(const __half2*)(h1l + (size_t)sC * 128));
      float2 fD = __half22float2(*(const __half2*)(h1l + (size_t)sD * 128));
      accx += fA.x * pA; accy += fA.y * pA;
      accx += fB.x * pB; accy += fB.y * pB;
      accx += fC.x * pC; accy += fC.y * pC;
      accx += fD.x * pD; accy += fD.y * pD;
    }
    for (; i < cnt; i++) {
      int s = s_lds[wave][i];
      float p = p_lds[wave][i][hsel];
      float2 f = __half22float2(*(const __half2*)(h1l + (size_t)s * 128));
      accx += f.x * p; accy += f.y * p;
    }
    asm volatile("s_waitcnt lgkmcnt(0)" ::: "memory");
  }

  // reduce den across lanes
#pragma unroll
  for (int h = 0; h < 8; h++) {
#pragma unroll
    for (int off = 32; off; off >>= 1) den[h] += __shfl_xor(den[h], off);
  }
  int hl = hsel & 3;
  float dA = (hl == 0) ? den[0] : (hl == 1) ? den[1] : (hl == 2) ? den[2] : den[3];
  float dB = (hl == 0) ? den[4] : (hl == 1) ? den[5] : (hl == 2) ? den[6] : den[7];
  float invd = 1.f / ((hsel & 4) ? dB : dA);
  float r0 = accx * invd, r1 = accy * invd;
  // sum over 8 heads (lanes sharing lane&7)
#pragma unroll
  for (int off = 8; off < 64; off <<= 1) {
    r0 += __shfl_xor(r0, off);
    r1 += __shfl_xor(r1, off);
  }
  int ch = (lane & 7) * 2;
  r0 = r0 * 0.125f + b1[ch];
  r1 = r1 * 0.125f + b1[ch + 1];
  r0 = r0 > 0.f ? r0 : __expf(r0) - 1.f;
  r1 = r1 > 0.f ? r1 : __expf(r1) - 1.f;

  // fused conv2 transform: h2[d][j] = sum_k r_k W2[k][j]
  float acc2 = 0.f;
#pragma unroll
  for (int k = 0; k < 16; k++) {
    float rs = (k & 1) ? r1 : r0;
    float rk = __shfl(rs, k >> 1);
    if (lane < N_CLS) acc2 += rk * W2[k * N_CLS + lane];
  }
  float sv = 0.f, dv = 0.f;
  if (lane < N_CLS) {
    h2[d * N_CLS + lane] = __float2half(acc2);
    sv = acc2 * att_s2[lane];
    dv = acc2 * att_d2[lane];
  }
#pragma unroll
  for (int off = 32; off; off >>= 1) {
    sv += __shfl_xor(sv, off);
    dv += __shfl_xor(dv, off);
  }
  if (lane == 0) { as2[d] = sv; ad2[d] = dv; }
}

// ---------------- conv2 aggregation + bias + log_softmax ----------------

__global__ __launch_bounds__(256) void k_agg2(
    const __half* __restrict__ h2, const float* __restrict__ as2,
    const float* __restrict__ ad2, const int* __restrict__ start,
    const int* __restrict__ esrc, const float* __restrict__ b2,
    const unsigned* __restrict__ as2maxEnc, float* __restrict__ out) {
  __shared__ float p_lds[4][64];
  __shared__ int s_lds[4][64];
  int wave = threadIdx.x >> 6, lane = threadIdx.x & 63;
  int d = blockIdx.x * 4 + wave;
  if (d >= N_NODES) return;
  int s0 = start[d];
  int deg = start[d + 1] - s0;
  float adv = ad2[d];
  float cm = decf(as2maxEnc[0]) + adv;
  cm = cm > 0.f ? cm : 0.2f * cm;

  float den = 0.f, acc = 0.f;
  for (int be = 0; be < deg; be += 64) {
    int cnt = min(64, deg - be);
    if (lane < cnt) {
      int s = esrc[s0 + be + lane];
      s_lds[wave][lane] = s;
      float e = as2[s] + adv;
      e = e > 0.f ? e : 0.2f * e;
      float p = __expf(e - cm);
      den += p;
      p_lds[wave][lane] = p;
    }
    asm volatile("s_waitcnt lgkmcnt(0)" ::: "memory");
    int i = 0;
    for (; i + 1 < cnt; i += 2) {
      int sA = s_lds[wave][i], sB = s_lds[wave][i + 1];
      float pA = p_lds[wave][i], pB = p_lds[wave][i + 1];
      if (lane < N_CLS) {
        float fA = __half2float(h2[(size_t)sA * N_CLS + lane]);
        float fB = __half2float(h2[(size_t)sB * N_CLS + lane]);
        acc += fA * pA;
        acc += fB * pB;
      }
    }
    if (i < cnt) {
      int s = s_lds[wave][i];
      float p = p_lds[wave][i];
      if (lane < N_CLS) acc += __half2float(h2[(size_t)s * N_CLS + lane]) * p;
    }
    asm volatile("s_waitcnt lgkmcnt(0)" ::: "memory");
  }
#pragma unroll
  for (int off = 32; off; off >>= 1) den += __shfl_xor(den, off);
  float iv = 1.f / den;

  float v = (lane < N_CLS) ? acc * iv + b2[lane] : -1e30f;
  float mx = v;
#pragma unroll
  for (int off = 32; off; off >>= 1) mx = fmaxf(mx, __shfl_xor(mx, off));
  float ex = (lane < N_CLS) ? __expf(v - mx) : 0.f;
  float sm = ex;
#pragma unroll
  for (int off = 32; off; off >>= 1) sm += __shfl_xor(sm, off);
  float lse = logf(sm);
  if (lane < N_CLS) out[d * N_CLS + lane] = (v - mx) - lse;
}

// ---------------- host launcher ----------------

extern "C" void kernel_launch(void* const* d_in, const int* in_sizes, int n_in,
                              void* d_out, int out_size, void* d_ws, size_t ws_size,
                              hipStream_t stream) {
  const float* x    = (const float*)d_in[0];
  const int*   ei   = (const int*)d_in[1];
  const float* W1   = (const float*)d_in[2];
  const float* as1w = (const float*)d_in[3];
  const float* ad1w = (const float*)d_in[4];
  const float* b1   = (const float*)d_in[5];
  const float* W2   = (const float*)d_in[6];
  const float* as2w = (const float*)d_in[7];
  const float* ad2w = (const float*)d_in[8];
  const float* b2   = (const float*)d_in[9];
  float* out = (float*)d_out;

  char* ws = (char*)d_ws;
  size_t off = 0;
  auto alloc = [&](size_t bytes) -> void* {
    void* p = ws + off;
    off += (bytes + 255) & ~(size_t)255;
    return p;
  };
  __half* h1   = (__half*)alloc((size_t)N_NODES * 128 * 2);
  float* as1   = (float*)alloc((size_t)N_NODES * 8 * 4);
  float* ad1   = (float*)alloc((size_t)N_NODES * 8 * 4);
  __half* h2   = (__half*)alloc((size_t)N_NODES * 40 * 2);
  float* as2   = (float*)alloc((size_t)N_NODES * 4);
  float* ad2   = (float*)alloc((size_t)N_NODES * 4);
  int* deg     = (int*)alloc((size_t)N_NODES * 4);
  int* start   = (int*)alloc((size_t)(N_NODES + 1) * 4);
  int* cursor  = (int*)alloc((size_t)N_NODES * 4);
  int* esrc    = (int*)alloc((size_t)ET * 4);
  unsigned* maxenc = (unsigned*)alloc(16 * 4);  // [0..7]=as1 per-head, [8]=as2

  (void)hipMemsetAsync(deg, 0, (size_t)N_NODES * 4, stream);
  (void)hipMemsetAsync(cursor, 0, (size_t)N_NODES * 4, stream);
  (void)hipMemsetAsync(maxenc, 0, 16 * 4, stream);

  int eb = (ET + 255) / 256;
  k_hist<<<eb, 256, 0, stream>>>(ei, deg);
  k_scan<<<1, 1024, 0, stream>>>(deg, start);
  k_scatter<<<eb, 256, 0, stream>>>(ei, start, cursor, esrc);

  k_xform1<<<(N_NODES + 63) / 64, 256, 0, stream>>>(x, W1, as1w, ad1w, h1, as1, ad1);
  k_maxas1<<<128, 256, 0, stream>>>(as1, maxenc);
  k_agg1<<<(N_NODES + 3) / 4, 256, 0, stream>>>(h1, as1, ad1, start, esrc, b1,
                                                W2, as2w, ad2w, maxenc,
                                                h2, as2, ad2);
  k_maxas2<<<64, 256, 0, stream>>>(as2, maxenc + 8);
  k_agg2<<<(N_NODES + 3) / 4, 256, 0, stream>>>(h2, as2, ad2, start, esrc, b2,
                                                maxenc + 8, out);
}